// Round 8
// baseline (394.888 us; speedup 1.0000x reference)
//
#include <hip/hip_runtime.h>
#include <hip/hip_cooperative_groups.h>

namespace cg = cooperative_groups;

typedef unsigned short ushort_t;
typedef unsigned int uint_t;
typedef __attribute__((ext_vector_type(8))) short short8;
typedef __attribute__((ext_vector_type(4))) float f32x4;

// Problem constants (B=1)
constexpr int DD = 8, HH = 24, WW = 24;
constexpr int NQ = DD * HH * WW;      // 4608
constexpr int CIN = 192;
constexpr int CQKV = 576;
constexpr int KP = 576;               // bf16x3 expanded K'
constexpr float ATT_SCALE = 0.17677669529663687f;
constexpr int NROW = DD * HH;         // 192

constexpr int NBLK = 512;             // mega-kernel grid (2 blocks/CU)

// ---------------------------------------------------------------------------
// bf16 helpers (RNE)
// ---------------------------------------------------------------------------
__device__ __forceinline__ ushort_t bf16h(float x) {
    uint_t u = __float_as_uint(x);
    u += 0x7FFFu + ((u >> 16) & 1u);
    return (ushort_t)(u >> 16);
}
__device__ __forceinline__ float bf16f(ushort_t h) {
    return __uint_as_float(((uint_t)h) << 16);
}
__device__ __forceinline__ void unpack8(uint4 u, float* f) {
    f[0] = __uint_as_float(u.x << 16); f[1] = __uint_as_float(u.x & 0xffff0000u);
    f[2] = __uint_as_float(u.y << 16); f[3] = __uint_as_float(u.y & 0xffff0000u);
    f[4] = __uint_as_float(u.z << 16); f[5] = __uint_as_float(u.z & 0xffff0000u);
    f[6] = __uint_as_float(u.w << 16); f[7] = __uint_as_float(u.w & 0xffff0000u);
}

// ---------------------------------------------------------------------------
// Shared-memory union: GEMM tiles / split buffers / transpose tile.
// ---------------------------------------------------------------------------
constexpr int KROW = 72;              // ushort stride per w (64 ch + 8 pad)
constexpr int RBUF = WW * KROW;       // 1728 ushorts

struct SmemGemm { ushort_t As[64][72]; ushort_t Bs[64][72]; };   // 18432 B
struct SmemSplit { ushort_t ksh[3 * RBUF]; ushort_t vsh[3 * RBUF]; }; // 20736 B
union Smem {
    SmemGemm g;
    float Ct[64][68];                 // 17408 B, aliases g after K-loop
    SmemSplit s;
    float T[32][36];
};

// Partial-entry bases (chunked split: CK = {2,3,4})
constexpr int EB0 = 0;
constexpr int EB1 = NROW * 2 * WW * 2;         // 18432
constexpr int EB2 = EB1 + NROW * 3 * WW * 2;   // 46080
constexpr int ETOT = EB2 + NROW * 4 * WW * 2;  // 82944

// ---------------------------------------------------------------------------
// Phase W: weight convert W (fp32 [192][N]) -> B' (bf16 [N][576] = [hi|hi|lo])
// tile task b in [0,144): 0..107 W_qkv, 108..143 W_proj. Uses tid<256.
// ---------------------------------------------------------------------------
__device__ __forceinline__
void dev_convert_w(const float* __restrict__ Wq, const float* __restrict__ Wp,
                   ushort_t* __restrict__ Bq, ushort_t* __restrict__ Bp,
                   int b, int tid, Smem* u)
{
    const float* W; ushort_t* Bb; int N; int kt, nt;
    if (b < 108) { W = Wq; Bb = Bq; N = CQKV; kt = b % 6; nt = b / 6; }
    else         { b -= 108; W = Wp; Bb = Bp; N = CIN; kt = b % 6; nt = b / 6; }
    const int k0 = kt * 32, n0 = nt * 32;

    if (tid < 256) {
        #pragma unroll
        for (int p = 0; p < 4; ++p) {
            int e = p * 256 + tid;
            int r = e >> 5, c = e & 31;
            u->T[c][r] = W[(long)(k0 + r) * N + n0 + c];
        }
    }
    __syncthreads();
    if (tid < 256) {
        const int n = tid >> 3;
        const int k4 = (tid & 7) * 4;
        float4 v = *(const float4*)(&u->T[n][k4]);
        ushort4 hv, lv;
        hv.x = bf16h(v.x); lv.x = bf16h(v.x - bf16f(hv.x));
        hv.y = bf16h(v.y); lv.y = bf16h(v.y - bf16f(hv.y));
        hv.z = bf16h(v.z); lv.z = bf16h(v.z - bf16f(hv.z));
        hv.w = bf16h(v.w); lv.w = bf16h(v.w - bf16f(hv.w));
        ushort_t* row = Bb + (long)(n0 + n) * KP + k0 + k4;
        *(ushort4*)(row)           = hv;
        *(ushort4*)(row + CIN)     = hv;
        *(ushort4*)(row + 2 * CIN) = lv;
    }
    __syncthreads();
}

// ---------------------------------------------------------------------------
// GEMM tile: C[64x64] at (tm,tn) = A[M][192] (bf16x3 expand) x B'[N][576]^T.
// 384 threads: tid<256 stage, waves 0-3 do MFMA, epilogue via Ct (aliases As/Bs).
// ---------------------------------------------------------------------------
template<bool BF16OUT>
__device__ __forceinline__
void dev_gemm_tile(const float* __restrict__ A, const ushort_t* __restrict__ Bb,
                   const float* __restrict__ bias, void* __restrict__ Cout,
                   int N, int tm, int tn, int tid, Smem* u)
{
    const int bm = tm * 64, bn = tn * 64;
    const int wv = tid >> 6;
    const int lane = tid & 63;
    const int lm = lane & 15;
    const int quad = lane >> 4;
    const int wr = (wv >> 1) * 32;    // valid for wv<4
    const int wc = (wv & 1) * 32;

    const int ar = tid >> 4;          // tid<256: 0..15 (+16/pass)
    const int ac4 = (tid & 15) * 4;
    const int br0 = tid >> 3;         // tid<256: 0..31
    const int bc0 = (tid & 7) * 8;

    f32x4 acc[2][2] = {};

    for (int kk = 0; kk < KP; kk += 64) {
        const int p3 = kk / 192;
        const int k0 = kk - p3 * 192;
        float4 av[4]; uint4 b0, b1;
        if (tid < 256) {
            #pragma unroll
            for (int p = 0; p < 4; ++p)
                av[p] = *(const float4*)(A + (long)(bm + ar + p * 16) * CIN + k0 + ac4);
            b0 = *(const uint4*)(Bb + (long)(bn + br0) * KP + kk + bc0);
            b1 = *(const uint4*)(Bb + (long)(bn + br0 + 32) * KP + kk + bc0);
        }
        __syncthreads();
        if (tid < 256) {
            #pragma unroll
            for (int p = 0; p < 4; ++p) {
                float4 v = av[p];
                ushort4 hv;
                hv.x = bf16h(v.x); hv.y = bf16h(v.y); hv.z = bf16h(v.z); hv.w = bf16h(v.w);
                if (p3 == 1) {
                    hv.x = bf16h(v.x - bf16f(hv.x));
                    hv.y = bf16h(v.y - bf16f(hv.y));
                    hv.z = bf16h(v.z - bf16f(hv.z));
                    hv.w = bf16h(v.w - bf16f(hv.w));
                }
                *(ushort4*)(&u->g.As[ar + p * 16][ac4]) = hv;
            }
            *(uint4*)(&u->g.Bs[br0][bc0]) = b0;
            *(uint4*)(&u->g.Bs[br0 + 32][bc0]) = b1;
        }
        __syncthreads();

        if (wv < 4) {
            #pragma unroll
            for (int ks = 0; ks < 64; ks += 32) {
                short8 af0 = *(const short8*)(&u->g.As[wr + lm][ks + quad * 8]);
                short8 af1 = *(const short8*)(&u->g.As[wr + 16 + lm][ks + quad * 8]);
                short8 bf0 = *(const short8*)(&u->g.Bs[wc + lm][ks + quad * 8]);
                short8 bf1 = *(const short8*)(&u->g.Bs[wc + 16 + lm][ks + quad * 8]);
                acc[0][0] = __builtin_amdgcn_mfma_f32_16x16x32_bf16(af0, bf0, acc[0][0], 0, 0, 0);
                acc[0][1] = __builtin_amdgcn_mfma_f32_16x16x32_bf16(af0, bf1, acc[0][1], 0, 0, 0);
                acc[1][0] = __builtin_amdgcn_mfma_f32_16x16x32_bf16(af1, bf0, acc[1][0], 0, 0, 0);
                acc[1][1] = __builtin_amdgcn_mfma_f32_16x16x32_bf16(af1, bf1, acc[1][1], 0, 0, 0);
            }
        }
    }

    __syncthreads();                  // all MFMA reads of As/Bs done (Ct aliases)
    if (wv < 4) {
        #pragma unroll
        for (int tc = 0; tc < 2; ++tc) {
            const float bv = bias[bn + wc + tc * 16 + lm];
            #pragma unroll
            for (int tr = 0; tr < 2; ++tr) {
                #pragma unroll
                for (int reg = 0; reg < 4; ++reg)
                    u->Ct[wr + tr * 16 + quad * 4 + reg][wc + tc * 16 + lm] = acc[tr][tc][reg] + bv;
            }
        }
    }
    __syncthreads();
    if (tid < 256) {
        const int orow = tid >> 4;
        const int oc4 = (tid & 15) * 4;
        #pragma unroll
        for (int p = 0; p < 4; ++p) {
            const int r = orow + p * 16;
            float4 v = *(const float4*)(&u->Ct[r][oc4]);
            if (BF16OUT) {
                ushort4 hv;
                hv.x = bf16h(v.x); hv.y = bf16h(v.y); hv.z = bf16h(v.z); hv.w = bf16h(v.w);
                *(ushort4*)((ushort_t*)Cout + (long)(bm + r) * N + bn + oc4) = hv;
            } else {
                *(float4*)((float*)Cout + (long)(bm + r) * N + bn + oc4) = v;
            }
        }
    }
    __syncthreads();
}

// ---------------------------------------------------------------------------
// Split chunk (R7-proven d8 core): active lanes tid<192 (w=t>>3, hd, d8);
// waves 3-5 ride the barriers.
// ---------------------------------------------------------------------------
template<int K>
__device__ __forceinline__
void dev_split_chunk(const ushort_t* __restrict__ qkv,
                     float* __restrict__ accs, float* __restrict__ stats,
                     int r, int c, int nchunks, int scale, int ebase,
                     int tid, SmemSplit* s)
{
    const bool act = tid < 192;
    const int w  = tid >> 3;          // 0..23 when act
    const int hd = (tid >> 2) & 1;
    const int d8 = tid & 3;

    const int i0 = 2 * c;
    const int ni = (K - i0) < 2 ? (K - i0) : 2;
    const int NT = ni * K;

    const int dq = r / HH, hq = r % HH;
    int sd = dq - K / 2; sd = sd < 0 ? 0 : (sd > DD - K ? DD - K : sd);
    int sh = hq - K / 2; sh = sh < 0 ? 0 : (sh > HH - K ? HH - K : sh);
    int sw = w  - K / 2; sw = sw < 0 ? 0 : (sw > WW - K ? WW - K : sw);

    float qf[8];
    if (act) {
        const int q = (dq * HH + hq) * WW + w;
        uint4 qu = *(const uint4*)(qkv + (long)q * CQKV + scale * 192 + hd * 32 + d8 * 8);
        unpack8(qu, qf);
        #pragma unroll
        for (int t = 0; t < 8; ++t) qf[t] *= ATT_SCALE;
    }

    const int lw = tid >> 3;
    const int c8 = (tid & 7) * 8;

    auto load_kv = [&](int buf, int t) {
        int i = i0 + t / K;
        int j = t - (t / K) * K;
        const ushort_t* p = qkv + (long)(((sd + i) * HH + (sh + j)) * WW + lw) * CQKV
                          + scale * 192 + c8;
        uint4 kk = *(const uint4*)(p + 64);
        uint4 vv = *(const uint4*)(p + 128);
        *(uint4*)(s->ksh + buf * RBUF + lw * KROW + c8) = kk;
        *(uint4*)(s->vsh + buf * RBUF + lw * KROW + c8) = vv;
    };

    float m = -1e30f, sum = 0.f;
    float acc[8] = {};
    const int choff = hd * 32 + d8 * 8;

    if (act) {
        load_kv(0, 0);
        if (NT > 1) load_kv(1, 1);
    }

    for (int t = 0; t < NT; ++t) {
        __syncthreads();
        if (act) {
            if (t + 2 < NT) load_kv((t + 2) % 3, t + 2);

            const ushort_t* kb = s->ksh + (t % 3) * RBUF + choff;
            float lg[K];
            #pragma unroll
            for (int n = 0; n < K; ++n) {
                uint4 ku = *(const uint4*)(kb + (sw + n) * KROW);
                float kf[8];
                unpack8(ku, kf);
                float p = qf[0] * kf[0] + qf[1] * kf[1] + qf[2] * kf[2] + qf[3] * kf[3]
                        + qf[4] * kf[4] + qf[5] * kf[5] + qf[6] * kf[6] + qf[7] * kf[7];
                p += __shfl_xor(p, 1);
                p += __shfl_xor(p, 2);
                lg[n] = p;
            }
            float mloc = lg[0];
            #pragma unroll
            for (int n = 1; n < K; ++n) mloc = fmaxf(mloc, lg[n]);
            float mnew = fmaxf(m, mloc);
            float alpha = __expf(m - mnew);
            m = mnew;
            sum *= alpha;
            #pragma unroll
            for (int d = 0; d < 8; ++d) acc[d] *= alpha;

            const ushort_t* vb = s->vsh + (t % 3) * RBUF + choff;
            #pragma unroll
            for (int n = 0; n < K; ++n) {
                float pr = __expf(lg[n] - mnew);
                sum += pr;
                uint4 vu = *(const uint4*)(vb + (sw + n) * KROW);
                float vf[8];
                unpack8(vu, vf);
                #pragma unroll
                for (int d = 0; d < 8; ++d) acc[d] += pr * vf[d];
            }
        }
    }
    __syncthreads();                  // next task reuses buffers

    if (act) {
        const int e = ebase + ((r * nchunks + c) * WW + w) * 2 + hd;
        if (d8 == 0) {
            stats[2 * e]     = m;
            stats[2 * e + 1] = sum;
        }
        float* ap = accs + (long)e * 32 + d8 * 8;
        *(float4*)(ap)     = make_float4(acc[0], acc[1], acc[2], acc[3]);
        *(float4*)(ap + 4) = make_float4(acc[4], acc[5], acc[6], acc[7]);
    }
}

__device__ __forceinline__
void split_task(int task, const ushort_t* qkv, float* accs, float* stats,
                int tid, SmemSplit* s)
{
    if (task < NROW * 4) {
        int r = task >> 2, c = task & 3;
        dev_split_chunk<7>(qkv, accs, stats, r, c, 4, 2, EB2, tid, s);
    } else if (task < NROW * 7) {
        int t = task - NROW * 4;
        int r = t / 3, c = t - (t / 3) * 3;
        dev_split_chunk<5>(qkv, accs, stats, r, c, 3, 1, EB1, tid, s);
    } else {
        int t = task - NROW * 7;
        int r = t >> 1, c = t & 1;
        dev_split_chunk<3>(qkv, accs, stats, r, c, 2, 0, EB0, tid, s);
    }
}

// ---------------------------------------------------------------------------
// Combine element n in [0, 221184): merge CK partials, write fp32 y.
// ---------------------------------------------------------------------------
__device__ __forceinline__
void dev_combine(const float* __restrict__ accs, const float* __restrict__ stats,
                 float* __restrict__ y, int n)
{
    constexpr int PER_SCALE = NROW * WW * 2 * 8;      // 73728
    const int scale = n / PER_SCALE;
    const int rem = n - scale * PER_SCALE;
    const int d4 = rem & 7;
    const int hd = (rem >> 3) & 1;
    const int t  = rem >> 4;
    const int w  = t % WW;
    const int row = t / WW;

    const int CK = scale == 0 ? 2 : (scale == 1 ? 3 : 4);
    const int ebase = scale == 0 ? EB0 : (scale == 1 ? EB1 : EB2);

    float mv[4], sv[4];
    float M = -1e30f;
    for (int c = 0; c < CK; ++c) {
        int e = ebase + ((row * CK + c) * WW + w) * 2 + hd;
        mv[c] = stats[2 * e];
        sv[c] = stats[2 * e + 1];
        M = fmaxf(M, mv[c]);
    }
    float S = 0.f;
    float4 o = make_float4(0.f, 0.f, 0.f, 0.f);
    for (int c = 0; c < CK; ++c) {
        int e = ebase + ((row * CK + c) * WW + w) * 2 + hd;
        float wgt = __expf(mv[c] - M);
        S += sv[c] * wgt;
        float4 a = *(const float4*)(accs + (long)e * 32 + d4 * 4);
        o.x += wgt * a.x; o.y += wgt * a.y; o.z += wgt * a.z; o.w += wgt * a.w;
    }
    const float rs = 1.0f / S;
    o.x *= rs; o.y *= rs; o.z *= rs; o.w *= rs;

    const int q = row * WW + w;
    *(float4*)(y + (long)q * CIN + scale * 64 + hd * 32 + d4 * 4) = o;
}

// ---------------------------------------------------------------------------
// Cooperative mega-kernel: all 5 phases, grid.sync() between.
// ---------------------------------------------------------------------------
__global__ __launch_bounds__(384, 3)
void mega_kernel(const float* x, const float* Wq, const float* bq,
                 const float* Wp, const float* bp, float* out,
                 float* accs, float* stats, float* y,
                 ushort_t* qkvb, ushort_t* Bbq, ushort_t* Bbp)
{
    __shared__ Smem u;
    cg::grid_group grid = cg::this_grid();
    const int bid = blockIdx.x;
    const int tid = threadIdx.x;

    // Phase W: 144 weight tiles
    if (bid < 144) dev_convert_w(Wq, Wp, Bbq, Bbp, bid, tid, &u);
    grid.sync();

    // Phase G1: 648 tiles (72 M x 9 N)
    for (int task = bid; task < 648; task += NBLK) {
        dev_gemm_tile<true>(x, Bbq, bq, qkvb, CQKV, task % 72, task / 72, tid, &u);
    }
    grid.sync();

    // Phase S: 1728 split tasks (K=7 first)
    for (int task = bid; task < 1728; task += NBLK) {
        split_task(task, qkvb, accs, stats, tid, &u.s);
    }
    grid.sync();

    // Phase C: 576 x 384 combine elements
    for (int task = bid; task < 576; task += NBLK) {
        dev_combine(accs, stats, y, task * 384 + tid);
    }
    grid.sync();

    // Phase G2: 216 tiles (72 M x 3 N)
    if (bid < 216) {
        dev_gemm_tile<false>(y, Bbp, bp, out, CIN, bid % 72, bid / 72, tid, &u);
    }
}

// ---------------------------------------------------------------------------
// Fallback wrappers (separate dispatches) if cooperative launch unavailable.
// ---------------------------------------------------------------------------
__global__ __launch_bounds__(384, 3)
void k_convert_w(const float* Wq, const float* Wp, ushort_t* Bq, ushort_t* Bp)
{
    __shared__ Smem u;
    dev_convert_w(Wq, Wp, Bq, Bp, blockIdx.x, threadIdx.x, &u);
}

template<bool BF16OUT>
__global__ __launch_bounds__(384, 3)
void k_gemm(const float* A, const ushort_t* Bb, const float* bias, void* C, int N)
{
    __shared__ Smem u;
    dev_gemm_tile<BF16OUT>(A, Bb, bias, C, N, blockIdx.x, blockIdx.y, threadIdx.x, &u);
}

__global__ __launch_bounds__(384, 3)
void k_split(const ushort_t* qkv, float* accs, float* stats)
{
    __shared__ Smem u;
    split_task(blockIdx.x, qkv, accs, stats, threadIdx.x, &u.s);
}

__global__ __launch_bounds__(384, 3)
void k_combine(const float* accs, const float* stats, float* y)
{
    dev_combine(accs, stats, y, blockIdx.x * 384 + threadIdx.x);
}

// ---------------------------------------------------------------------------
extern "C" void kernel_launch(void* const* d_in, const int* in_sizes, int n_in,
                              void* d_out, int out_size, void* d_ws, size_t ws_size,
                              hipStream_t stream)
{
    const float* x      = (const float*)d_in[0];
    const float* W_qkv  = (const float*)d_in[1];
    const float* b_qkv  = (const float*)d_in[2];
    const float* W_proj = (const float*)d_in[3];
    const float* b_proj = (const float*)d_in[4];
    float* out = (float*)d_out;

    // workspace (~21 MB; ws >= 22.5 MB proven)
    float* accs    = (float*)d_ws;                         // ETOT*32 fl
    float* stats   = accs + (long)ETOT * 32;               // 2*ETOT fl
    float* y       = stats + 2 * ETOT;                     // NQ*192 fl
    ushort_t* qkvb = (ushort_t*)(y + (long)NQ * CIN);      // NQ*576 us
    ushort_t* Wbq  = qkvb + (long)NQ * CQKV;               // 576*576 us
    ushort_t* Wbp  = Wbq + (long)CQKV * KP;                // 192*576 us

    void* args[] = {(void*)&x, (void*)&W_qkv, (void*)&b_qkv, (void*)&W_proj,
                    (void*)&b_proj, (void*)&out, (void*)&accs, (void*)&stats,
                    (void*)&y, (void*)&qkvb, (void*)&Wbq, (void*)&Wbp};
    hipError_t err = hipLaunchCooperativeKernel((void*)mega_kernel,
                                                dim3(NBLK), dim3(384),
                                                args, 0, stream);
    if (err != hipSuccess) {
        // Fallback: same phases as separate dispatches.
        k_convert_w<<<dim3(144), 384, 0, stream>>>(W_qkv, W_proj, Wbq, Wbp);
        k_gemm<true><<<dim3(72, 9), 384, 0, stream>>>(x, Wbq, b_qkv, qkvb, CQKV);
        k_split<<<dim3(1728), 384, 0, stream>>>(qkvb, accs, stats);
        k_combine<<<dim3(576), 384, 0, stream>>>(accs, stats, y);
        k_gemm<false><<<dim3(72, 3), 384, 0, stream>>>(y, Wbp, b_proj, out, CIN);
    }
}

// Round 9
// 148.000 us; speedup vs baseline: 2.6682x; 2.6682x over previous
//
#include <hip/hip_runtime.h>

typedef unsigned short ushort_t;
typedef unsigned int uint_t;
typedef __attribute__((ext_vector_type(8))) short short8;
typedef __attribute__((ext_vector_type(4))) float f32x4;

// Problem constants (B=1)
constexpr int DD = 8, HH = 24, WW = 24;
constexpr int NQ = DD * HH * WW;      // 4608
constexpr int CIN = 192;
constexpr int CQKV = 576;
constexpr int KP = 576;               // bf16x3 expanded K'
constexpr float ATT_SCALE = 0.17677669529663687f;
constexpr int NROW = DD * HH;         // 192

// ---------------------------------------------------------------------------
// bf16 helpers (RNE)
// ---------------------------------------------------------------------------
__device__ __forceinline__ ushort_t bf16h(float x) {
    uint_t u = __float_as_uint(x);
    u += 0x7FFFu + ((u >> 16) & 1u);
    return (ushort_t)(u >> 16);
}
__device__ __forceinline__ float bf16f(ushort_t h) {
    return __uint_as_float(((uint_t)h) << 16);
}
__device__ __forceinline__ void unpack8(uint4 u, float* f) {
    f[0] = __uint_as_float(u.x << 16); f[1] = __uint_as_float(u.x & 0xffff0000u);
    f[2] = __uint_as_float(u.y << 16); f[3] = __uint_as_float(u.y & 0xffff0000u);
    f[4] = __uint_as_float(u.z << 16); f[5] = __uint_as_float(u.z & 0xffff0000u);
    f[6] = __uint_as_float(u.w << 16); f[7] = __uint_as_float(u.w & 0xffff0000u);
}
// 8 fp32 -> short8 bf16 fragment (hi, or lo residual if lo_phase)
__device__ __forceinline__ short8 afrag8(const float* p, bool lo_phase) {
    float4 a = *(const float4*)(p);
    float4 b = *(const float4*)(p + 4);
    float f[8] = {a.x, a.y, a.z, a.w, b.x, b.y, b.z, b.w};
    short8 r;
    #pragma unroll
    for (int i = 0; i < 8; ++i) {
        ushort_t h = bf16h(f[i]);
        if (lo_phase) h = bf16h(f[i] - bf16f(h));
        r[i] = (short)h;
    }
    return r;
}

// Partial-entry bases (chunked split: CK = {2,3,4})
constexpr int EB0 = 0;
constexpr int EB1 = NROW * 2 * WW * 2;         // 18432
constexpr int EB2 = EB1 + NROW * 3 * WW * 2;   // 46080
constexpr int ETOT = EB2 + NROW * 4 * WW * 2;  // 82944

// ---------------------------------------------------------------------------
// D1: GEMM1 = x[4608][192] (bf16x3: hi|lo|hi) x W_qkv (bf16x3: hi|hi|lo,
// transposed+converted INLINE from fp32) + b_qkv -> qkvb bf16 [4608][576].
// BM=BN=64, BK=64, 256 threads (4 waves 2x2), 16x16x32 bf16 MFMA.
// ---------------------------------------------------------------------------
__global__ __launch_bounds__(256)
void gemm1_kernel(const float* __restrict__ A, const float* __restrict__ W,
                  const float* __restrict__ bias, ushort_t* __restrict__ Cout)
{
    __shared__ ushort_t As[64][72];
    __shared__ ushort_t Bs[64][72];
    __shared__ float Ct[64][68];

    const int tid = threadIdx.x;
    const int bm = blockIdx.x * 64;
    const int bn = blockIdx.y * 64;
    const int N = CQKV;

    const int wv = tid >> 6;
    const int lane = tid & 63;
    const int lm = lane & 15;
    const int quad = lane >> 4;
    const int wr = (wv >> 1) * 32;
    const int wc = (wv & 1) * 32;

    // A staging: (row, float-quad), 4 passes of 16 rows
    const int ar = tid >> 4;             // 0..15
    const int ac4 = (tid & 15) * 4;
    // W staging: (k-row, n-quad), 4 passes of 16 k-rows; written transposed
    const int kr = ar;
    const int nc4 = ac4;

    f32x4 acc[2][2] = {};

    for (int kk = 0; kk < KP; kk += 64) {
        const int p3 = kk / 192;
        const int k0 = kk - p3 * 192;
        // prefetch (before barrier: overlaps previous MFMA burst)
        float4 av[4], wv4[4];
        #pragma unroll
        for (int p = 0; p < 4; ++p) {
            av[p]  = *(const float4*)(A + (long)(bm + ar + p * 16) * CIN + k0 + ac4);
            wv4[p] = *(const float4*)(W + (long)(k0 + kr + p * 16) * N + bn + nc4);
        }
        __syncthreads();
        #pragma unroll
        for (int p = 0; p < 4; ++p) {
            // A' phases: 0 -> hi, 1 -> lo, 2 -> hi
            float4 v = av[p];
            ushort4 hv;
            hv.x = bf16h(v.x); hv.y = bf16h(v.y); hv.z = bf16h(v.z); hv.w = bf16h(v.w);
            if (p3 == 1) {
                hv.x = bf16h(v.x - bf16f(hv.x));
                hv.y = bf16h(v.y - bf16f(hv.y));
                hv.z = bf16h(v.z - bf16f(hv.z));
                hv.w = bf16h(v.w - bf16f(hv.w));
            }
            *(ushort4*)(&As[ar + p * 16][ac4]) = hv;
            // B' phases: 0 -> hi, 1 -> hi, 2 -> lo ; store TRANSPOSED
            float4 u = wv4[p];
            ushort4 bw;
            bw.x = bf16h(u.x); bw.y = bf16h(u.y); bw.z = bf16h(u.z); bw.w = bf16h(u.w);
            if (p3 == 2) {
                bw.x = bf16h(u.x - bf16f(bw.x));
                bw.y = bf16h(u.y - bf16f(bw.y));
                bw.z = bf16h(u.z - bf16f(bw.z));
                bw.w = bf16h(u.w - bf16f(bw.w));
            }
            const int kc = kr + p * 16;
            Bs[nc4 + 0][kc] = bw.x;
            Bs[nc4 + 1][kc] = bw.y;
            Bs[nc4 + 2][kc] = bw.z;
            Bs[nc4 + 3][kc] = bw.w;
        }
        __syncthreads();

        #pragma unroll
        for (int ks = 0; ks < 64; ks += 32) {
            short8 af0 = *(const short8*)(&As[wr + lm][ks + quad * 8]);
            short8 af1 = *(const short8*)(&As[wr + 16 + lm][ks + quad * 8]);
            short8 bf0 = *(const short8*)(&Bs[wc + lm][ks + quad * 8]);
            short8 bf1 = *(const short8*)(&Bs[wc + 16 + lm][ks + quad * 8]);
            acc[0][0] = __builtin_amdgcn_mfma_f32_16x16x32_bf16(af0, bf0, acc[0][0], 0, 0, 0);
            acc[0][1] = __builtin_amdgcn_mfma_f32_16x16x32_bf16(af0, bf1, acc[0][1], 0, 0, 0);
            acc[1][0] = __builtin_amdgcn_mfma_f32_16x16x32_bf16(af1, bf0, acc[1][0], 0, 0, 0);
            acc[1][1] = __builtin_amdgcn_mfma_f32_16x16x32_bf16(af1, bf1, acc[1][1], 0, 0, 0);
        }
    }

    // epilogue: C/D layout col=lane&15, row=quad*4+reg [m89] -> LDS bounce
    #pragma unroll
    for (int tc = 0; tc < 2; ++tc) {
        const float bv = bias[bn + wc + tc * 16 + lm];
        #pragma unroll
        for (int tr = 0; tr < 2; ++tr) {
            #pragma unroll
            for (int reg = 0; reg < 4; ++reg)
                Ct[wr + tr * 16 + quad * 4 + reg][wc + tc * 16 + lm] = acc[tr][tc][reg] + bv;
        }
    }
    __syncthreads();
    const int orow = tid >> 4;
    const int oc4 = (tid & 15) * 4;
    #pragma unroll
    for (int p = 0; p < 4; ++p) {
        const int r = orow + p * 16;
        float4 v = *(const float4*)(&Ct[r][oc4]);
        ushort4 hv;
        hv.x = bf16h(v.x); hv.y = bf16h(v.y); hv.z = bf16h(v.z); hv.w = bf16h(v.w);
        *(ushort4*)(Cout + (long)(bm + r) * N + bn + oc4) = hv;
    }
}

// ---------------------------------------------------------------------------
// D2: attention split (R7-proven, unchanged). bf16 LDS, triple-buffered,
// 192 threads: w = t>>3, hd = (t>>2)&1, d8 = t&3; 8 channels/thread.
// ---------------------------------------------------------------------------
constexpr int KROW = 72;              // ushort stride per w (64 ch + 8 pad)
constexpr int RBUF = WW * KROW;       // 1728 ushorts

template<int K>
__device__ __forceinline__
void split_chunk(const ushort_t* __restrict__ qkv,
                 float* __restrict__ accs, float* __restrict__ stats,
                 int r, int c, int nchunks, int scale, int ebase,
                 int w, int hd, int d8, int tid,
                 ushort_t* __restrict__ ksh, ushort_t* __restrict__ vsh)
{
    const int i0 = 2 * c;
    const int ni = (K - i0) < 2 ? (K - i0) : 2;
    const int NT = ni * K;

    const int dq = r / HH, hq = r % HH;
    int sd = dq - K / 2; sd = sd < 0 ? 0 : (sd > DD - K ? DD - K : sd);
    int sh = hq - K / 2; sh = sh < 0 ? 0 : (sh > HH - K ? HH - K : sh);
    int sw = w  - K / 2; sw = sw < 0 ? 0 : (sw > WW - K ? WW - K : sw);

    const int q = (dq * HH + hq) * WW + w;

    uint4 qu = *(const uint4*)(qkv + (long)q * CQKV + scale * 192 + hd * 32 + d8 * 8);
    float qf[8];
    unpack8(qu, qf);
    #pragma unroll
    for (int t = 0; t < 8; ++t) qf[t] *= ATT_SCALE;

    const int lw = tid >> 3;
    const int c8 = (tid & 7) * 8;

    auto load_kv = [&](int buf, int t) {
        int i = i0 + t / K;
        int j = t - (t / K) * K;
        const ushort_t* p = qkv + (long)(((sd + i) * HH + (sh + j)) * WW + lw) * CQKV
                          + scale * 192 + c8;
        uint4 kk = *(const uint4*)(p + 64);
        uint4 vv = *(const uint4*)(p + 128);
        *(uint4*)(ksh + buf * RBUF + lw * KROW + c8) = kk;
        *(uint4*)(vsh + buf * RBUF + lw * KROW + c8) = vv;
    };

    float m = -1e30f, sum = 0.f;
    float acc[8] = {};
    const int choff = hd * 32 + d8 * 8;

    load_kv(0, 0);
    if (NT > 1) load_kv(1, 1);

    for (int t = 0; t < NT; ++t) {
        __syncthreads();
        if (t + 2 < NT) load_kv((t + 2) % 3, t + 2);

        const ushort_t* kb = ksh + (t % 3) * RBUF + choff;
        float lg[K];
        #pragma unroll
        for (int n = 0; n < K; ++n) {
            uint4 ku = *(const uint4*)(kb + (sw + n) * KROW);
            float kf[8];
            unpack8(ku, kf);
            float p = qf[0] * kf[0] + qf[1] * kf[1] + qf[2] * kf[2] + qf[3] * kf[3]
                    + qf[4] * kf[4] + qf[5] * kf[5] + qf[6] * kf[6] + qf[7] * kf[7];
            p += __shfl_xor(p, 1);
            p += __shfl_xor(p, 2);
            lg[n] = p;
        }
        float mloc = lg[0];
        #pragma unroll
        for (int n = 1; n < K; ++n) mloc = fmaxf(mloc, lg[n]);
        float mnew = fmaxf(m, mloc);
        float alpha = __expf(m - mnew);
        m = mnew;
        sum *= alpha;
        #pragma unroll
        for (int d = 0; d < 8; ++d) acc[d] *= alpha;

        const ushort_t* vb = vsh + (t % 3) * RBUF + choff;
        #pragma unroll
        for (int n = 0; n < K; ++n) {
            float pr = __expf(lg[n] - mnew);
            sum += pr;
            uint4 vu = *(const uint4*)(vb + (sw + n) * KROW);
            float vf[8];
            unpack8(vu, vf);
            #pragma unroll
            for (int d = 0; d < 8; ++d) acc[d] += pr * vf[d];
        }
    }

    const int e = ebase + ((r * nchunks + c) * WW + w) * 2 + hd;
    if (d8 == 0) {
        stats[2 * e]     = m;
        stats[2 * e + 1] = sum;
    }
    float* ap = accs + (long)e * 32 + d8 * 8;
    *(float4*)(ap)     = make_float4(acc[0], acc[1], acc[2], acc[3]);
    *(float4*)(ap + 4) = make_float4(acc[4], acc[5], acc[6], acc[7]);
}

__global__ __launch_bounds__(192)
void na3d_split_kernel(const ushort_t* __restrict__ qkv,
                       float* __restrict__ accs, float* __restrict__ stats)
{
    __shared__ alignas(16) ushort_t ksh[3 * RBUF];
    __shared__ alignas(16) ushort_t vsh[3 * RBUF];

    const int tid = threadIdx.x;
    const int w  = tid >> 3;
    const int hd = (tid >> 2) & 1;
    const int d8 = tid & 3;

    const int bid = blockIdx.x;            // 1728 total; longest (K=7) first
    if (bid < NROW * 4) {
        int r = bid >> 2, c = bid & 3;
        split_chunk<7>(qkv, accs, stats, r, c, 4, 2, EB2, w, hd, d8, tid, ksh, vsh);
    } else if (bid < NROW * 4 + NROW * 3) {
        int t = bid - NROW * 4;
        int r = t / 3, c = t - (t / 3) * 3;
        split_chunk<5>(qkv, accs, stats, r, c, 3, 1, EB1, w, hd, d8, tid, ksh, vsh);
    } else {
        int t = bid - NROW * 7;
        int r = t >> 1, c = t & 1;
        split_chunk<3>(qkv, accs, stats, r, c, 2, 0, EB0, w, hd, d8, tid, ksh, vsh);
    }
}

// ---------------------------------------------------------------------------
// D3: combine + GEMM2 fused. Each block (tm, tn) first combines its 64-row
// y-tile (fp32, in LDS; 3x redundant across the 3 n-tiles -> no sync needed),
// then runs the MFMA K-loop: A-fragments read from the LDS y-tile with
// in-register hi/lo conversion; B staged inline from fp32 W_proj (transposed).
// Epilogue Ct aliases the y-tile (dead after last MFMA).
// ---------------------------------------------------------------------------
__global__ __launch_bounds__(256)
void combine_gemm2_kernel(const float* __restrict__ accs, const float* __restrict__ stats,
                          const float* __restrict__ W, const float* __restrict__ bias,
                          float* __restrict__ out)
{
    __shared__ float ytile[64][196];     // 64 q-rows x 192 ch (+4 pad)
    __shared__ ushort_t Bs[64][72];

    const int tid = threadIdx.x;
    const int bm = blockIdx.x * 64;
    const int bn = blockIdx.y * 64;

    // ---- Phase A: combine 64 q-rows into ytile (4 threads per q, 48 ch each)
    {
        const int ql = tid >> 2;
        const int q = bm + ql;
        const int row = q / WW;
        const int w = q - row * WW;
        const int chb = (tid & 3) * 48;
        #pragma unroll
        for (int c4 = 0; c4 < 12; ++c4) {
            const int ch = chb + c4 * 4;
            const int scale = ch >> 6;
            const int rem = ch & 63;
            const int hd = rem >> 5;
            const int d4 = (rem >> 2) & 7;
            const int CK = scale == 0 ? 2 : (scale == 1 ? 3 : 4);
            const int ebase = scale == 0 ? EB0 : (scale == 1 ? EB1 : EB2);

            float mv[4], sv[4];
            float M = -1e30f;
            for (int c = 0; c < CK; ++c) {
                int e = ebase + ((row * CK + c) * WW + w) * 2 + hd;
                mv[c] = stats[2 * e];
                sv[c] = stats[2 * e + 1];
                M = fmaxf(M, mv[c]);
            }
            float S = 0.f;
            float4 o = make_float4(0.f, 0.f, 0.f, 0.f);
            for (int c = 0; c < CK; ++c) {
                int e = ebase + ((row * CK + c) * WW + w) * 2 + hd;
                float wgt = __expf(mv[c] - M);
                S += sv[c] * wgt;
                float4 a = *(const float4*)(accs + (long)e * 32 + d4 * 4);
                o.x += wgt * a.x; o.y += wgt * a.y; o.z += wgt * a.z; o.w += wgt * a.w;
            }
            const float rs = 1.0f / S;
            o.x *= rs; o.y *= rs; o.z *= rs; o.w *= rs;
            *(float4*)(&ytile[ql][ch]) = o;
        }
    }
    __syncthreads();

    // ---- Phase B: GEMM over K' = 576
    const int wv = tid >> 6;
    const int lane = tid & 63;
    const int lm = lane & 15;
    const int quad = lane >> 4;
    const int wr = (wv >> 1) * 32;
    const int wc = (wv & 1) * 32;

    const int kr = tid >> 4;             // 0..15
    const int nc4 = (tid & 15) * 4;

    f32x4 acc[2][2] = {};

    for (int kk = 0; kk < KP; kk += 64) {
        const int p3 = kk / 192;
        const int k0 = kk - p3 * 192;
        float4 wv4[4];
        #pragma unroll
        for (int p = 0; p < 4; ++p)
            wv4[p] = *(const float4*)(W + (long)(k0 + kr + p * 16) * CIN + bn + nc4);
        __syncthreads();                 // previous Bs fully consumed
        #pragma unroll
        for (int p = 0; p < 4; ++p) {
            // B' phases: 0 -> hi, 1 -> hi, 2 -> lo ; store TRANSPOSED
            float4 u = wv4[p];
            ushort4 bw;
            bw.x = bf16h(u.x); bw.y = bf16h(u.y); bw.z = bf16h(u.z); bw.w = bf16h(u.w);
            if (p3 == 2) {
                bw.x = bf16h(u.x - bf16f(bw.x));
                bw.y = bf16h(u.y - bf16f(bw.y));
                bw.z = bf16h(u.z - bf16f(bw.z));
                bw.w = bf16h(u.w - bf16f(bw.w));
            }
            const int kc = kr + p * 16;
            Bs[nc4 + 0][kc] = bw.x;
            Bs[nc4 + 1][kc] = bw.y;
            Bs[nc4 + 2][kc] = bw.z;
            Bs[nc4 + 3][kc] = bw.w;
        }
        __syncthreads();

        const bool alo = (p3 == 1);      // A' phases: 0 hi, 1 lo, 2 hi
        #pragma unroll
        for (int ks = 0; ks < 64; ks += 32) {
            short8 af0 = afrag8(&ytile[wr + lm][k0 + ks + quad * 8], alo);
            short8 af1 = afrag8(&ytile[wr + 16 + lm][k0 + ks + quad * 8], alo);
            short8 bf0 = *(const short8*)(&Bs[wc + lm][ks + quad * 8]);
            short8 bf1 = *(const short8*)(&Bs[wc + 16 + lm][ks + quad * 8]);
            acc[0][0] = __builtin_amdgcn_mfma_f32_16x16x32_bf16(af0, bf0, acc[0][0], 0, 0, 0);
            acc[0][1] = __builtin_amdgcn_mfma_f32_16x16x32_bf16(af0, bf1, acc[0][1], 0, 0, 0);
            acc[1][0] = __builtin_amdgcn_mfma_f32_16x16x32_bf16(af1, bf0, acc[1][0], 0, 0, 0);
            acc[1][1] = __builtin_amdgcn_mfma_f32_16x16x32_bf16(af1, bf1, acc[1][1], 0, 0, 0);
        }
    }

    __syncthreads();                     // all MFMA reads of ytile done
    float* Ct = &ytile[0][0];            // reuse as Ct[64][68]

    #pragma unroll
    for (int tc = 0; tc < 2; ++tc) {
        const float bv = bias[bn + wc + tc * 16 + lm];
        #pragma unroll
        for (int tr = 0; tr < 2; ++tr) {
            #pragma unroll
            for (int reg = 0; reg < 4; ++reg)
                Ct[(wr + tr * 16 + quad * 4 + reg) * 68 + wc + tc * 16 + lm] = acc[tr][tc][reg] + bv;
        }
    }
    __syncthreads();
    const int orow = tid >> 4;
    const int oc4 = (tid & 15) * 4;
    #pragma unroll
    for (int p = 0; p < 4; ++p) {
        const int r = orow + p * 16;
        float4 v = *(const float4*)(&Ct[r * 68 + oc4]);
        *(float4*)(out + (long)(bm + r) * CIN + bn + oc4) = v;
    }
}

// ---------------------------------------------------------------------------
extern "C" void kernel_launch(void* const* d_in, const int* in_sizes, int n_in,
                              void* d_out, int out_size, void* d_ws, size_t ws_size,
                              hipStream_t stream)
{
    const float* x      = (const float*)d_in[0];
    const float* W_qkv  = (const float*)d_in[1];
    const float* b_qkv  = (const float*)d_in[2];
    const float* W_proj = (const float*)d_in[3];
    const float* b_proj = (const float*)d_in[4];
    float* out = (float*)d_out;

    // workspace (~16.6 MB; >= 22.5 MB available proven in earlier rounds)
    float* accs    = (float*)d_ws;                         // ETOT*32 fl
    float* stats   = accs + (long)ETOT * 32;               // 2*ETOT fl
    ushort_t* qkvb = (ushort_t*)(stats + 2 * ETOT);        // NQ*576 us

    // D1: qkv = x @ W_qkv + b_qkv  (inline W convert; bf16 out)
    gemm1_kernel<<<dim3(NQ / 64, CQKV / 64), 256, 0, stream>>>(x, W_qkv, b_qkv, qkvb);

    // D2: attention split -> partials
    na3d_split_kernel<<<dim3(NROW * (4 + 3 + 2)), 192, 0, stream>>>(qkvb, accs, stats);

    // D3: combine + (y @ W_proj + b_proj) fused -> fp32 out
    combine_gemm2_kernel<<<dim3(NQ / 64, CIN / 64), 256, 0, stream>>>(accs, stats, W_proj, b_proj, out);
}

// Round 10
// 133.210 us; speedup vs baseline: 2.9644x; 1.1110x over previous
//
#include <hip/hip_runtime.h>

typedef unsigned short ushort_t;
typedef unsigned int uint_t;
typedef __attribute__((ext_vector_type(8))) short short8;
typedef __attribute__((ext_vector_type(4))) float f32x4;

// Problem constants (B=1)
constexpr int DD = 8, HH = 24, WW = 24;
constexpr int NQ = DD * HH * WW;      // 4608
constexpr int CIN = 192;
constexpr int CQKV = 576;
constexpr int KP = 576;               // bf16x3 expanded K'
constexpr float ATT_SCALE = 0.17677669529663687f;
constexpr int NROW = DD * HH;         // 192

// ---------------------------------------------------------------------------
// bf16 helpers (RNE)
// ---------------------------------------------------------------------------
__device__ __forceinline__ ushort_t bf16h(float x) {
    uint_t u = __float_as_uint(x);
    u += 0x7FFFu + ((u >> 16) & 1u);
    return (ushort_t)(u >> 16);
}
__device__ __forceinline__ float bf16f(ushort_t h) {
    return __uint_as_float(((uint_t)h) << 16);
}
__device__ __forceinline__ void unpack8(uint4 u, float* f) {
    f[0] = __uint_as_float(u.x << 16); f[1] = __uint_as_float(u.x & 0xffff0000u);
    f[2] = __uint_as_float(u.y << 16); f[3] = __uint_as_float(u.y & 0xffff0000u);
    f[4] = __uint_as_float(u.z << 16); f[5] = __uint_as_float(u.z & 0xffff0000u);
    f[6] = __uint_as_float(u.w << 16); f[7] = __uint_as_float(u.w & 0xffff0000u);
}

// Partial-entry bases (chunked split: CK = {2,3,4})
constexpr int EB0 = 0;
constexpr int EB1 = NROW * 2 * WW * 2;         // 18432
constexpr int EB2 = EB1 + NROW * 3 * WW * 2;   // 46080
constexpr int ETOT = EB2 + NROW * 4 * WW * 2;  // 82944

// ---------------------------------------------------------------------------
// D0: fused weight convert (R7-proven, unchanged):
// W (fp32 [192][N]) -> B' (bf16 [N][576] = [hi|hi|lo]).
// blocks 0..107 -> W_qkv; 108..143 -> W_proj.
// ---------------------------------------------------------------------------
__global__ __launch_bounds__(256)
void convert_w_kernel(const float* __restrict__ Wq, const float* __restrict__ Wp,
                      ushort_t* __restrict__ Bq, ushort_t* __restrict__ Bp)
{
    __shared__ float T[32][36];
    int b = blockIdx.x;
    const float* W; ushort_t* Bb; int N;
    int kt, nt;
    if (b < 108) { W = Wq; Bb = Bq; N = CQKV; kt = b % 6; nt = b / 6; }
    else         { b -= 108; W = Wp; Bb = Bp; N = CIN; kt = b % 6; nt = b / 6; }
    const int k0 = kt * 32, n0 = nt * 32;
    const int tid = threadIdx.x;

    #pragma unroll
    for (int p = 0; p < 4; ++p) {
        int e = p * 256 + tid;
        int r = e >> 5, c = e & 31;
        T[c][r] = W[(long)(k0 + r) * N + n0 + c];
    }
    __syncthreads();
    const int n = tid >> 3;
    const int k4 = (tid & 7) * 4;
    float4 v = *(const float4*)(&T[n][k4]);
    ushort4 hv, lv;
    hv.x = bf16h(v.x); lv.x = bf16h(v.x - bf16f(hv.x));
    hv.y = bf16h(v.y); lv.y = bf16h(v.y - bf16f(hv.y));
    hv.z = bf16h(v.z); lv.z = bf16h(v.z - bf16f(hv.z));
    hv.w = bf16h(v.w); lv.w = bf16h(v.w - bf16f(hv.w));
    ushort_t* row = Bb + (long)(n0 + n) * KP + k0 + k4;
    *(ushort4*)(row)           = hv;   // pairs Ah
    *(ushort4*)(row + CIN)     = hv;   // pairs Al
    *(ushort4*)(row + 2 * CIN) = lv;   // pairs Ah
}

// ---------------------------------------------------------------------------
// D1: GEMM1 (R7-proven, unchanged): qkv = x @ W_qkv + b_qkv -> bf16.
// fp32 A consumed directly (hi/lo conversion in staging), pre-converted B'.
// ---------------------------------------------------------------------------
__global__ __launch_bounds__(256)
void gemm1_kernel(const float* __restrict__ A, const ushort_t* __restrict__ Bb,
                  const float* __restrict__ bias, ushort_t* __restrict__ Cout)
{
    __shared__ ushort_t As[64][72];
    __shared__ ushort_t Bs[64][72];
    __shared__ float Ct[64][68];

    const int tid = threadIdx.x;
    const int bm = blockIdx.x * 64;
    const int bn = blockIdx.y * 64;
    const int N = CQKV;

    const int wv = tid >> 6;
    const int lane = tid & 63;
    const int lm = lane & 15;
    const int quad = lane >> 4;
    const int wr = (wv >> 1) * 32;
    const int wc = (wv & 1) * 32;

    const int ar = tid >> 4;
    const int ac4 = (tid & 15) * 4;
    const int br0 = tid >> 3;
    const int bc0 = (tid & 7) * 8;

    f32x4 acc[2][2] = {};

    for (int kk = 0; kk < KP; kk += 64) {
        const int p3 = kk / 192;
        const int k0 = kk - p3 * 192;
        float4 av[4];
        #pragma unroll
        for (int p = 0; p < 4; ++p)
            av[p] = *(const float4*)(A + (long)(bm + ar + p * 16) * CIN + k0 + ac4);
        uint4 b0 = *(const uint4*)(Bb + (long)(bn + br0) * KP + kk + bc0);
        uint4 b1 = *(const uint4*)(Bb + (long)(bn + br0 + 32) * KP + kk + bc0);
        __syncthreads();
        #pragma unroll
        for (int p = 0; p < 4; ++p) {
            float4 v = av[p];
            ushort4 hv;
            hv.x = bf16h(v.x); hv.y = bf16h(v.y); hv.z = bf16h(v.z); hv.w = bf16h(v.w);
            if (p3 == 1) {
                hv.x = bf16h(v.x - bf16f(hv.x));
                hv.y = bf16h(v.y - bf16f(hv.y));
                hv.z = bf16h(v.z - bf16f(hv.z));
                hv.w = bf16h(v.w - bf16f(hv.w));
            }
            *(ushort4*)(&As[ar + p * 16][ac4]) = hv;
        }
        *(uint4*)(&Bs[br0][bc0]) = b0;
        *(uint4*)(&Bs[br0 + 32][bc0]) = b1;
        __syncthreads();

        #pragma unroll
        for (int ks = 0; ks < 64; ks += 32) {
            short8 af0 = *(const short8*)(&As[wr + lm][ks + quad * 8]);
            short8 af1 = *(const short8*)(&As[wr + 16 + lm][ks + quad * 8]);
            short8 bf0 = *(const short8*)(&Bs[wc + lm][ks + quad * 8]);
            short8 bf1 = *(const short8*)(&Bs[wc + 16 + lm][ks + quad * 8]);
            acc[0][0] = __builtin_amdgcn_mfma_f32_16x16x32_bf16(af0, bf0, acc[0][0], 0, 0, 0);
            acc[0][1] = __builtin_amdgcn_mfma_f32_16x16x32_bf16(af0, bf1, acc[0][1], 0, 0, 0);
            acc[1][0] = __builtin_amdgcn_mfma_f32_16x16x32_bf16(af1, bf0, acc[1][0], 0, 0, 0);
            acc[1][1] = __builtin_amdgcn_mfma_f32_16x16x32_bf16(af1, bf1, acc[1][1], 0, 0, 0);
        }
    }

    #pragma unroll
    for (int tc = 0; tc < 2; ++tc) {
        const float bv = bias[bn + wc + tc * 16 + lm];
        #pragma unroll
        for (int tr = 0; tr < 2; ++tr) {
            #pragma unroll
            for (int reg = 0; reg < 4; ++reg)
                Ct[wr + tr * 16 + quad * 4 + reg][wc + tc * 16 + lm] = acc[tr][tc][reg] + bv;
        }
    }
    __syncthreads();
    const int orow = tid >> 4;
    const int oc4 = (tid & 15) * 4;
    #pragma unroll
    for (int p = 0; p < 4; ++p) {
        const int r = orow + p * 16;
        float4 v = *(const float4*)(&Ct[r][oc4]);
        ushort4 hv;
        hv.x = bf16h(v.x); hv.y = bf16h(v.y); hv.z = bf16h(v.z); hv.w = bf16h(v.w);
        *(ushort4*)(Cout + (long)(bm + r) * N + bn + oc4) = hv;
    }
}

// ---------------------------------------------------------------------------
// D2: attention split (R7-proven, byte-identical). bf16 LDS, triple-buffered,
// 192 threads: w = t>>3, hd = (t>>2)&1, d8 = t&3; 8 channels/thread.
// ---------------------------------------------------------------------------
constexpr int KROW = 72;              // ushort stride per w (64 ch + 8 pad)
constexpr int RBUF = WW * KROW;       // 1728 ushorts

template<int K>
__device__ __forceinline__
void split_chunk(const ushort_t* __restrict__ qkv,
                 float* __restrict__ accs, float* __restrict__ stats,
                 int r, int c, int nchunks, int scale, int ebase,
                 int w, int hd, int d8, int tid,
                 ushort_t* __restrict__ ksh, ushort_t* __restrict__ vsh)
{
    const int i0 = 2 * c;
    const int ni = (K - i0) < 2 ? (K - i0) : 2;
    const int NT = ni * K;

    const int dq = r / HH, hq = r % HH;
    int sd = dq - K / 2; sd = sd < 0 ? 0 : (sd > DD - K ? DD - K : sd);
    int sh = hq - K / 2; sh = sh < 0 ? 0 : (sh > HH - K ? HH - K : sh);
    int sw = w  - K / 2; sw = sw < 0 ? 0 : (sw > WW - K ? WW - K : sw);

    const int q = (dq * HH + hq) * WW + w;

    uint4 qu = *(const uint4*)(qkv + (long)q * CQKV + scale * 192 + hd * 32 + d8 * 8);
    float qf[8];
    unpack8(qu, qf);
    #pragma unroll
    for (int t = 0; t < 8; ++t) qf[t] *= ATT_SCALE;

    const int lw = tid >> 3;
    const int c8 = (tid & 7) * 8;

    auto load_kv = [&](int buf, int t) {
        int i = i0 + t / K;
        int j = t - (t / K) * K;
        const ushort_t* p = qkv + (long)(((sd + i) * HH + (sh + j)) * WW + lw) * CQKV
                          + scale * 192 + c8;
        uint4 kk = *(const uint4*)(p + 64);
        uint4 vv = *(const uint4*)(p + 128);
        *(uint4*)(ksh + buf * RBUF + lw * KROW + c8) = kk;
        *(uint4*)(vsh + buf * RBUF + lw * KROW + c8) = vv;
    };

    float m = -1e30f, sum = 0.f;
    float acc[8] = {};
    const int choff = hd * 32 + d8 * 8;

    load_kv(0, 0);
    if (NT > 1) load_kv(1, 1);

    for (int t = 0; t < NT; ++t) {
        __syncthreads();
        if (t + 2 < NT) load_kv((t + 2) % 3, t + 2);

        const ushort_t* kb = ksh + (t % 3) * RBUF + choff;
        float lg[K];
        #pragma unroll
        for (int n = 0; n < K; ++n) {
            uint4 ku = *(const uint4*)(kb + (sw + n) * KROW);
            float kf[8];
            unpack8(ku, kf);
            float p = qf[0] * kf[0] + qf[1] * kf[1] + qf[2] * kf[2] + qf[3] * kf[3]
                    + qf[4] * kf[4] + qf[5] * kf[5] + qf[6] * kf[6] + qf[7] * kf[7];
            p += __shfl_xor(p, 1);
            p += __shfl_xor(p, 2);
            lg[n] = p;
        }
        float mloc = lg[0];
        #pragma unroll
        for (int n = 1; n < K; ++n) mloc = fmaxf(mloc, lg[n]);
        float mnew = fmaxf(m, mloc);
        float alpha = __expf(m - mnew);
        m = mnew;
        sum *= alpha;
        #pragma unroll
        for (int d = 0; d < 8; ++d) acc[d] *= alpha;

        const ushort_t* vb = vsh + (t % 3) * RBUF + choff;
        #pragma unroll
        for (int n = 0; n < K; ++n) {
            float pr = __expf(lg[n] - mnew);
            sum += pr;
            uint4 vu = *(const uint4*)(vb + (sw + n) * KROW);
            float vf[8];
            unpack8(vu, vf);
            #pragma unroll
            for (int d = 0; d < 8; ++d) acc[d] += pr * vf[d];
        }
    }

    const int e = ebase + ((r * nchunks + c) * WW + w) * 2 + hd;
    if (d8 == 0) {
        stats[2 * e]     = m;
        stats[2 * e + 1] = sum;
    }
    float* ap = accs + (long)e * 32 + d8 * 8;
    *(float4*)(ap)     = make_float4(acc[0], acc[1], acc[2], acc[3]);
    *(float4*)(ap + 4) = make_float4(acc[4], acc[5], acc[6], acc[7]);
}

__global__ __launch_bounds__(192)
void na3d_split_kernel(const ushort_t* __restrict__ qkv,
                       float* __restrict__ accs, float* __restrict__ stats)
{
    __shared__ alignas(16) ushort_t ksh[3 * RBUF];
    __shared__ alignas(16) ushort_t vsh[3 * RBUF];

    const int tid = threadIdx.x;
    const int w  = tid >> 3;
    const int hd = (tid >> 2) & 1;
    const int d8 = tid & 3;

    const int bid = blockIdx.x;            // 1728 total; longest (K=7) first
    if (bid < NROW * 4) {
        int r = bid >> 2, c = bid & 3;
        split_chunk<7>(qkv, accs, stats, r, c, 4, 2, EB2, w, hd, d8, tid, ksh, vsh);
    } else if (bid < NROW * 4 + NROW * 3) {
        int t = bid - NROW * 4;
        int r = t / 3, c = t - (t / 3) * 3;
        split_chunk<5>(qkv, accs, stats, r, c, 3, 1, EB1, w, hd, d8, tid, ksh, vsh);
    } else {
        int t = bid - NROW * 7;
        int r = t >> 1, c = t & 1;
        split_chunk<3>(qkv, accs, stats, r, c, 2, 0, EB0, w, hd, d8, tid, ksh, vsh);
    }
}

// ---------------------------------------------------------------------------
// D3: combine + GEMM2 fused, conversion OUT of the K-loop.
// Phase A: combine this block's 64-row y-tile; write hi/lo bf16 into
//          yhi[64][200] / ylo[64][200] (exact bf16x3 split, same as R7).
// Phase B: R7 GEMM2 K-loop; A-fragments = direct short8 reads from yhi
//          (phases 0,2) or ylo (phase 1); Bs copied from pre-converted Wbp.
// Epilogue Ct aliases yhi (dead after last MFMA).
// ---------------------------------------------------------------------------
constexpr int YST = 200;              // ushort stride (192 + 8 pad; 400B rows)

__global__ __launch_bounds__(256)
void combine_gemm2_kernel(const float* __restrict__ accs, const float* __restrict__ stats,
                          const ushort_t* __restrict__ Bb, const float* __restrict__ bias,
                          float* __restrict__ out)
{
    __shared__ union {
        struct { ushort_t yhi[64][YST]; ushort_t ylo[64][YST]; ushort_t Bs[64][72]; } s;
        float Ct[64][68];             // aliases yhi after K-loop
    } u;

    const int tid = threadIdx.x;
    const int bm = blockIdx.x * 64;
    const int bn = blockIdx.y * 64;

    // ---- Phase A: combine (4 threads per q-row, 48 ch each) ----
    {
        const int ql = tid >> 2;
        const int q = bm + ql;
        const int row = q / WW;
        const int w = q - row * WW;
        const int chb = (tid & 3) * 48;
        #pragma unroll
        for (int c4 = 0; c4 < 12; ++c4) {
            const int ch = chb + c4 * 4;
            const int scale = ch >> 6;
            const int rem = ch & 63;
            const int hd = rem >> 5;
            const int d4 = (rem >> 2) & 7;
            const int CK = scale == 0 ? 2 : (scale == 1 ? 3 : 4);
            const int ebase = scale == 0 ? EB0 : (scale == 1 ? EB1 : EB2);

            float mv[4], sv[4];
            float M = -1e30f;
            for (int c = 0; c < CK; ++c) {
                int e = ebase + ((row * CK + c) * WW + w) * 2 + hd;
                mv[c] = stats[2 * e];
                sv[c] = stats[2 * e + 1];
                M = fmaxf(M, mv[c]);
            }
            float S = 0.f;
            float4 o = make_float4(0.f, 0.f, 0.f, 0.f);
            for (int c = 0; c < CK; ++c) {
                int e = ebase + ((row * CK + c) * WW + w) * 2 + hd;
                float wgt = __expf(mv[c] - M);
                S += sv[c] * wgt;
                float4 a = *(const float4*)(accs + (long)e * 32 + d4 * 4);
                o.x += wgt * a.x; o.y += wgt * a.y; o.z += wgt * a.z; o.w += wgt * a.w;
            }
            const float rs = 1.0f / S;
            o.x *= rs; o.y *= rs; o.z *= rs; o.w *= rs;

            ushort4 hv, lv;
            hv.x = bf16h(o.x); lv.x = bf16h(o.x - bf16f(hv.x));
            hv.y = bf16h(o.y); lv.y = bf16h(o.y - bf16f(hv.y));
            hv.z = bf16h(o.z); lv.z = bf16h(o.z - bf16f(hv.z));
            hv.w = bf16h(o.w); lv.w = bf16h(o.w - bf16f(hv.w));
            *(ushort4*)(&u.s.yhi[ql][ch]) = hv;
            *(ushort4*)(&u.s.ylo[ql][ch]) = lv;
        }
    }
    __syncthreads();

    // ---- Phase B: GEMM over K' = 576 ----
    const int wv = tid >> 6;
    const int lane = tid & 63;
    const int lm = lane & 15;
    const int quad = lane >> 4;
    const int wr = (wv >> 1) * 32;
    const int wc = (wv & 1) * 32;

    const int br0 = tid >> 3;
    const int bc0 = (tid & 7) * 8;

    f32x4 acc[2][2] = {};

    for (int kk = 0; kk < KP; kk += 64) {
        const int p3 = kk / 192;
        const int k0 = kk - p3 * 192;
        uint4 b0 = *(const uint4*)(Bb + (long)(bn + br0) * KP + kk + bc0);
        uint4 b1 = *(const uint4*)(Bb + (long)(bn + br0 + 32) * KP + kk + bc0);
        __syncthreads();                 // previous Bs fully consumed
        *(uint4*)(&u.s.Bs[br0][bc0]) = b0;
        *(uint4*)(&u.s.Bs[br0 + 32][bc0]) = b1;
        __syncthreads();

        const ushort_t* ybase = (p3 == 1) ? &u.s.ylo[0][0] : &u.s.yhi[0][0];
        #pragma unroll
        for (int ks = 0; ks < 64; ks += 32) {
            short8 af0 = *(const short8*)(ybase + (wr + lm) * YST + k0 + ks + quad * 8);
            short8 af1 = *(const short8*)(ybase + (wr + 16 + lm) * YST + k0 + ks + quad * 8);
            short8 bf0 = *(const short8*)(&u.s.Bs[wc + lm][ks + quad * 8]);
            short8 bf1 = *(const short8*)(&u.s.Bs[wc + 16 + lm][ks + quad * 8]);
            acc[0][0] = __builtin_amdgcn_mfma_f32_16x16x32_bf16(af0, bf0, acc[0][0], 0, 0, 0);
            acc[0][1] = __builtin_amdgcn_mfma_f32_16x16x32_bf16(af0, bf1, acc[0][1], 0, 0, 0);
            acc[1][0] = __builtin_amdgcn_mfma_f32_16x16x32_bf16(af1, bf0, acc[1][0], 0, 0, 0);
            acc[1][1] = __builtin_amdgcn_mfma_f32_16x16x32_bf16(af1, bf1, acc[1][1], 0, 0, 0);
        }
    }

    __syncthreads();                     // all MFMA reads of yhi/ylo done
    #pragma unroll
    for (int tc = 0; tc < 2; ++tc) {
        const float bv = bias[bn + wc + tc * 16 + lm];
        #pragma unroll
        for (int tr = 0; tr < 2; ++tr) {
            #pragma unroll
            for (int reg = 0; reg < 4; ++reg)
                u.Ct[wr + tr * 16 + quad * 4 + reg][wc + tc * 16 + lm] = acc[tr][tc][reg] + bv;
        }
    }
    __syncthreads();
    const int orow = tid >> 4;
    const int oc4 = (tid & 15) * 4;
    #pragma unroll
    for (int p = 0; p < 4; ++p) {
        const int r = orow + p * 16;
        float4 v = *(const float4*)(&u.Ct[r][oc4]);
        *(float4*)(out + (long)(bm + r) * CIN + bn + oc4) = v;
    }
}

// ---------------------------------------------------------------------------
extern "C" void kernel_launch(void* const* d_in, const int* in_sizes, int n_in,
                              void* d_out, int out_size, void* d_ws, size_t ws_size,
                              hipStream_t stream)
{
    const float* x      = (const float*)d_in[0];
    const float* W_qkv  = (const float*)d_in[1];
    const float* b_qkv  = (const float*)d_in[2];
    const float* W_proj = (const float*)d_in[3];
    const float* b_proj = (const float*)d_in[4];
    float* out = (float*)d_out;

    // workspace (~17.6 MB; >= 22.5 MB proven available)
    float* accs    = (float*)d_ws;                         // ETOT*32 fl
    float* stats   = accs + (long)ETOT * 32;               // 2*ETOT fl
    ushort_t* qkvb = (ushort_t*)(stats + 2 * ETOT);        // NQ*576 us
    ushort_t* Wbq  = qkvb + (long)NQ * CQKV;               // 576*576 us
    ushort_t* Wbp  = Wbq + (long)CQKV * KP;                // 192*576 us

    // D0: weight conversion (one dispatch, both weights)
    convert_w_kernel<<<dim3(144), 256, 0, stream>>>(W_qkv, W_proj, Wbq, Wbp);

    // D1: qkv = x @ W_qkv + b_qkv -> bf16
    gemm1_kernel<<<dim3(NQ / 64, CQKV / 64), 256, 0, stream>>>(x, Wbq, b_qkv, qkvb);

    // D2: attention split -> partials
    na3d_split_kernel<<<dim3(NROW * (4 + 3 + 2)), 192, 0, stream>>>(qkvb, accs, stats);

    // D3: combine + (y @ W_proj + b_proj) fused -> fp32 out
    combine_gemm2_kernel<<<dim3(NQ / 64, CIN / 64), 256, 0, stream>>>(accs, stats, Wbp, b_proj, out);
}